// Round 8
// baseline (127.049 us; speedup 1.0000x reference)
//
#include <hip/hip_runtime.h>
#include <hip/hip_fp16.h>
#include <array>

// Problem constants (reference: H=64, M=N=128, k=9, w=3)
constexpr int HZ   = 64;
constexpr int NN   = 128;
constexpr int P    = HZ * NN * NN;    // 1,048,576 voxels
constexpr int KSEL = 9;
constexpr int NCOL = 27;              // 3x3x3 window

typedef _Float16 f16x2 __attribute__((ext_vector_type(2)));

// Fused tile geometry: core 4z x 8y x 32x = 1024 voxels per 512-thread block.
constexpr int CZ = 4, CY = 8, CX = 32;
constexpr int NCORE = CZ * CY * CX;         // 1024
constexpr int RZ = 6, RY = 10, RX = 34;     // row halo (core +1 each side)
constexpr int NROWS = RZ * RY * RX;         // 2040 sorted rows per block
constexpr int NHALO = NROWS - NCORE;        // 1016 pure-halo rows
constexpr int IZ = 8, IY = 12, IXW = 40;    // input halo (row halo +1, x 16B-aligned)
constexpr int NIN = IZ * IY * IXW;          // 3840 floats
constexpr int NIN16 = IZ * IY * (IXW / 4);  // 960 16-byte staging groups

// ---------------------------------------------------------------------------
// Batcher merge-exchange network for n=27 + backward dead-CE pruning.
// ---------------------------------------------------------------------------
constexpr int compute_nce(int n) {
  int t = 0; while ((1 << t) < n) ++t;
  int cnt = 0;
  for (int p = 1 << (t - 1); p > 0; p >>= 1) {
    int q = 1 << (t - 1), r = 0, d = p;
    while (true) {
      for (int i = 0; i < n - d; ++i)
        if ((i & p) == r) ++cnt;
      if (q == p) break;
      d = q - p; r = p; q >>= 1;
    }
  }
  return cnt;
}
constexpr int NCE_FULL = compute_nce(NCOL);   // 155

struct CEPair { unsigned char a, b; };
constexpr std::array<CEPair, NCE_FULL> make_net() {
  std::array<CEPair, NCE_FULL> net{};
  int t = 0; while ((1 << t) < NCOL) ++t;
  int k = 0;
  for (int p = 1 << (t - 1); p > 0; p >>= 1) {
    int q = 1 << (t - 1), r = 0, d = p;
    while (true) {
      for (int i = 0; i < NCOL - d; ++i)
        if ((i & p) == r) {
          net[k].a = (unsigned char)i;
          net[k].b = (unsigned char)(i + d);
          ++k;
        }
      if (q == p) break;
      d = q - p; r = p; q >>= 1;
    }
  }
  return net;
}
constexpr auto FULLNET = make_net();

constexpr int count_pruned() {
  bool needed[NCOL] = {};
  for (int i = 0; i < KSEL; ++i) needed[i] = true;
  int cnt = 0;
  for (int e = NCE_FULL - 1; e >= 0; --e) {
    const int a = FULLNET[e].a, b = FULLNET[e].b;
    if (needed[a] || needed[b]) { needed[a] = true; needed[b] = true; ++cnt; }
  }
  return cnt;
}
constexpr int NCE = count_pruned();

constexpr std::array<CEPair, NCE> make_pruned() {
  bool needed[NCOL] = {};
  for (int i = 0; i < KSEL; ++i) needed[i] = true;
  std::array<bool, NCE_FULL> keep{};
  for (int e = NCE_FULL - 1; e >= 0; --e) {
    const int a = FULLNET[e].a, b = FULLNET[e].b;
    if (needed[a] || needed[b]) { keep[e] = true; needed[a] = true; needed[b] = true; }
  }
  std::array<CEPair, NCE> out{};
  int k = 0;
  for (int e = 0; e < NCE_FULL; ++e) if (keep[e]) out[k++] = FULLNET[e];
  return out;
}
constexpr auto NET = make_pruned();

// Pure-halo row ids (rows whose col-bits nobody needs): 1016 x u16 = 2 KB.
constexpr std::array<unsigned short, NHALO> make_halo() {
  std::array<unsigned short, NHALO> t{};
  int k = 0;
  for (int r = 0; r < NROWS; ++r) {
    const int rz = r / (RY * RX), rem = r % (RY * RX);
    const int ry = rem / RX, rx = rem % RX;
    const bool core = (rz >= 1 && rz <= CZ) && (ry >= 1 && ry <= CY) &&
                      (rx >= 1 && rx <= CX);
    if (!core) t[k++] = (unsigned short)r;
  }
  return t;
}
__device__ constexpr auto HALO = make_halo();

// ---------------------------------------------------------------------------
// Async global->LDS DMA helper (16 B wide, lane-linear dest).
// ---------------------------------------------------------------------------
typedef const __attribute__((address_space(1))) unsigned GU;
typedef __attribute__((address_space(3))) unsigned LU;

__device__ __forceinline__ void g2l16(const void* g, void* l) {
  __builtin_amdgcn_global_load_lds((GU*)g, (LU*)l, 16, 0, 0);
}

// ---------------------------------------------------------------------------
// Per-row sort: key = db<<32 | col<<27 | vbits>>5 (63 bits, sign bit 0).
// CE = u64 compare + 4x cndmask (v_cmp_lt_u64 ~4cyc + 4x2cyc = ~12cyc) --
// replaces R7's f64 fmin/fmax pair, measured at ~8cyc/instr = 16cyc/CE
// (R7 counters: ~2500 VALU-cyc/sort only fits quarter-rate f64 min/max).
// u64 order of these 63-bit non-negative keys == f64 order -> bit-identical.
// Order = (db, col) exactly -> exact NumPy stable order.
// ---------------------------------------------------------------------------
__device__ __forceinline__ void sort_row(
    const float* __restrict__ in_t, int rz, int ry, int rx,
    unsigned od[4], unsigned& h8, unsigned& lo, unsigned& hi) {
  const float center = in_t[((rz + 1) * IY + (ry + 1)) * IXW + rx + 3];

  unsigned long long key[NCOL];
  #pragma unroll
  for (int c = 0; c < NCOL; ++c) {
    const int czi = c / 9, cyi = (c / 3) % 3, cxi = c % 3;
    const float v = in_t[((rz + czi) * IY + (ry + cyi)) * IXW + rx + cxi + 2];
    const unsigned vb = __float_as_uint(v);
    const unsigned db = __float_as_uint(v - center) & 0x7fffffffu;
    key[c] = ((unsigned long long)db << 32) |
             (((unsigned)c << 27) | (vb >> 5));
  }

  #pragma unroll
  for (int e = 0; e < NCE; ++e) {
    const int a = NET[e].a, b = NET[e].b;
    const unsigned long long ka = key[a], kb = key[b];
    const bool lt = ka < kb;            // v_cmp_lt_u64 -> vcc
    key[a] = lt ? ka : kb;              // 2x v_cndmask_b32
    key[b] = lt ? kb : ka;              // 2x v_cndmask_b32
  }

  od[0] = od[1] = od[2] = od[3] = 0; h8 = 0; lo = 0; hi = 0;
  #pragma unroll
  for (int k = 0; k < KSEL; ++k) {
    const unsigned kl = (unsigned)key[k];
    const unsigned c  = (kl >> 27) & 31u;
    const unsigned vbits = (kl & 0x07ffffffu) << 5;
    const unsigned hb = (unsigned)__half_as_ushort(__float2half(__uint_as_float(vbits)));
    if (k < 8) od[k >> 1] |= hb << ((k & 1) * 16);
    else       h8 = hb;
    if (k < 6) lo |= c << (5 * k);
    else       hi |= c << (5 * (k - 6));
  }
}

// ---------------------------------------------------------------------------
// Fused kernel, 18 B/row LDS edition (52.1 KB -> 3 blocks/CU at VGPR<=64).
//   tA  [2040 x 16B] : halves h0..h7          (gathered by neighbors)
//   tB0h[2040 x 2B]  : h8                     (gathered by neighbors)
//   in_t[3840 x 4B]  : input halo
// Own-core-row col-bits live in registers; sort phase is straight-line
// (two explicit own-row sorts + rolled halo loop). NO launch_bounds
// min-occupancy clause (R6: capping forced the 27xu64 key array to scratch).
// ---------------------------------------------------------------------------
__global__ __launch_bounds__(512) void buildk_fused4(
    const float* __restrict__ anat,
    const float* __restrict__ ksig,
    float* __restrict__ out) {
  __shared__ __align__(16) unsigned char ldsb[NROWS * 16 + NROWS * 2 + NIN * 4];
  unsigned*       tA   = (unsigned*)ldsb;                          // 32640 B
  unsigned short* tB0h = (unsigned short*)(ldsb + NROWS * 16);     //  4080 B
  float*          in_t = (float*)(ldsb + NROWS * 16 + NROWS * 2);  // 15360 B

  const int tid = threadIdx.x;

  // 1024 blocks = 16 zt x 16 yt x 4 xt tiles; XCD-aware bijective swizzle.
  const int blk = blockIdx.x;
  const int swz = ((blk & 7) << 7) | (blk >> 3);
  const int zt   = swz >> 6;
  const int rest = swz & 63;
  const int y0   = ((rest >> 2) & 15) << 3;
  const int x0   = (rest & 3) << 5;
  const int z0   = zt << 2;

  const int xl = tid & 31;
  const int yl = (tid >> 5) & 7;
  const int zl = tid >> 8;                    // 0..1

  // ---- Stage input halo: 960 x 16B lane-linear DMA ----
  #pragma unroll
  for (int s = 0; s < 2; ++s) {
    const unsigned q = (unsigned)(s * 512 + tid);
    if (q < (unsigned)NIN16) {
      const unsigned p = q / 10u;              // plane-row 0..95
      const unsigned t = q - 10u * p;          // 16B group 0..9
      const unsigned iz = p / 12u;
      const unsigned iy = p - 12u * iz;
      const int zz = (z0 + (int)iz - 2) & (HZ - 1);
      const int yy = (y0 + (int)iy - 2) & (NN - 1);
      const int xb = (x0 - 4 + 4 * (int)t) & (NN - 1);
      g2l16(&anat[(zz << 14) | (yy << 7) | xb], &in_t[q * 4]);
    }
  }
  __syncthreads();

  // ---- Sort phase: 2 own core rows (straight-line) + 1016 halo rows ----
  unsigned lo0, hi0, lo1, hi1;
  {
    unsigned od[4], h8;
    const int rz = 2 * zl + 1, ry = yl + 1, rx = xl + 1;
    const int ru = (rz * RY + ry) * RX + rx;
    sort_row(in_t, rz, ry, rx, od, h8, lo0, hi0);
    *(uint4*)&tA[(unsigned)ru * 4] = make_uint4(od[0], od[1], od[2], od[3]);
    tB0h[ru] = (unsigned short)h8;
  }
  {
    unsigned od[4], h8;
    const int rz = 2 * zl + 2, ry = yl + 1, rx = xl + 1;
    const int ru = (rz * RY + ry) * RX + rx;
    sort_row(in_t, rz, ry, rx, od, h8, lo1, hi1);
    *(uint4*)&tA[(unsigned)ru * 4] = make_uint4(od[0], od[1], od[2], od[3]);
    tB0h[ru] = (unsigned short)h8;
  }
  #pragma unroll 1
  for (int s = 0; s < 2; ++s) {
    const int idx = s * 512 + tid;
    if (idx < NHALO) {
      const int ru = (int)HALO[idx];
      const int rz = ru / (RY * RX);
      const int rem = ru - (RY * RX) * rz;
      const int ry = rem / RX, rx = rem - RX * ry;
      unsigned od[4], h8, lo, hi;
      sort_row(in_t, rz, ry, rx, od, h8, lo, hi);
      *(uint4*)&tA[(unsigned)ru * 4] = make_uint4(od[0], od[1], od[2], od[3]);
      tB0h[ru] = (unsigned short)h8;
    }
  }
  __syncthreads();

  // ---- Weights phase: 2 core voxels per thread ----
  const float ks = ksig[0];
  const _Float16 epsh = (_Float16)1e-6f;
  const f16x2 eps2 = {epsh, epsh};

  float res[2][9];

  #pragma unroll
  for (int vz = 0; vz < 2; ++vz) {
    const int zv = 2 * zl + vz;               // core z offset 0..3
    const unsigned lo = (vz == 0) ? lo0 : lo1;
    const unsigned hi = (vz == 0) ? hi0 : hi1;

    const int rho_own = ((zv + 1) * RY + (yl + 1)) * RX + (xl + 1);
    const uint4 a = *(const uint4*)&tA[rho_own * 4];
    const unsigned b0 = (unsigned)tB0h[rho_own];
    f16x2 wh[5];
    wh[0] = __builtin_bit_cast(f16x2, a.x);
    wh[1] = __builtin_bit_cast(f16x2, a.y);
    wh[2] = __builtin_bit_cast(f16x2, a.z);
    wh[3] = __builtin_bit_cast(f16x2, a.w);
    wh[4] = __builtin_bit_cast(f16x2, b0);    // hi half = 0 pad

    // Decode all 9 neighbor row addresses, then batch-issue all 18 reads.
    int rho[KSEL];
    #pragma unroll
    for (int j = 0; j < KSEL; ++j) {
      const unsigned c = (j < 6) ? ((lo >> (5 * j)) & 31u)
                                 : ((hi >> (5 * (j - 6))) & 31u);
      const unsigned czi = (c * 57u) >> 9;
      const unsigned rem = c - 9u * czi;
      const unsigned cyi = (rem * 11u) >> 5;
      const unsigned cxi = rem - 3u * cyi;
      rho[j] = ((zv + (int)czi) * RY + (yl + (int)cyi)) * RX + (xl + (int)cxi);
    }
    uint4 na[KSEL];
    unsigned nb[KSEL];
    #pragma unroll
    for (int j = 0; j < KSEL; ++j) {
      na[j] = *(const uint4*)&tA[rho[j] * 4];
      nb[j] = (unsigned)tB0h[rho[j]];
    }

    // sigma with ddof=1 (two-pass, matches jnp.std).
    float ws[KSEL];
    #pragma unroll
    for (int l = 0; l < KSEL; ++l) ws[l] = (float)wh[l >> 1][l & 1];
    float mean = 0.f;
    #pragma unroll
    for (int l = 0; l < KSEL; ++l) mean += ws[l];
    mean *= (1.0f / 9.0f);
    float var = 0.f;
    #pragma unroll
    for (int l = 0; l < KSEL; ++l) { const float t = ws[l] - mean; var += t * t; }
    var *= (1.0f / 8.0f);
    const float sigma = sqrtf(var);

    // log2(e) folded in: e[j] = exp2(logit[j] - mx)
    const float inv2 = (sigma == 0.f)
        ? 0.f
        : 1.4426950408889634f / (2.0f * ks * ks * sigma * sigma);

    float logit[KSEL];
    #pragma unroll
    for (int j = 0; j < KSEL; ++j) {
      const f16x2 nh0 = __builtin_bit_cast(f16x2, na[j].x);
      const f16x2 nh1 = __builtin_bit_cast(f16x2, na[j].y);
      const f16x2 nh2 = __builtin_bit_cast(f16x2, na[j].z);
      const f16x2 nh3 = __builtin_bit_cast(f16x2, na[j].w);
      const f16x2 nh4 = __builtin_bit_cast(f16x2, nb[j]);
      float s = 0.f;
      f16x2 dd;
      dd = (wh[0] - nh0) + eps2; s = __builtin_amdgcn_fdot2(dd, dd, s, false);
      dd = (wh[1] - nh1) + eps2; s = __builtin_amdgcn_fdot2(dd, dd, s, false);
      dd = (wh[2] - nh2) + eps2; s = __builtin_amdgcn_fdot2(dd, dd, s, false);
      dd = (wh[3] - nh3) + eps2; s = __builtin_amdgcn_fdot2(dd, dd, s, false);
      dd = (wh[4] - nh4) + eps2; s = __builtin_amdgcn_fdot2(dd, dd, s, false);
      logit[j] = -s * inv2;
    }

    // softmax (exp2 domain) over the 9 logits
    float mx = logit[0];
    #pragma unroll
    for (int j = 1; j < KSEL; ++j) mx = fmaxf(mx, logit[j]);
    float sum = 0.f;
    float e[KSEL];
    #pragma unroll
    for (int j = 0; j < KSEL; ++j) { e[j] = exp2f(logit[j] - mx); sum += e[j]; }
    const float rs = 1.0f / sum;
    #pragma unroll
    for (int j = 0; j < KSEL; ++j) res[vz][j] = e[j] * rs;
  }

  // ---- Output staging through LDS -> coalesced float4 stores ----
  __syncthreads();                            // rows LDS now dead
  float* tf = (float*)ldsb;                   // 36864 B < 52080 B total
  #pragma unroll
  for (int vz = 0; vz < 2; ++vz) {
    const int zv = 2 * zl + vz;
    const int pos = (zv << 8) + (yl << 5) + xl;   // zv-major staging order
    #pragma unroll
    for (int j = 0; j < KSEL; ++j) tf[pos * KSEL + j] = res[vz][j];
  }
  __syncthreads();

  const float4* tf4 = (const float4*)ldsb;
  #pragma unroll
  for (int s = 0; s < 5; ++s) {
    const unsigned q = (unsigned)(s * 512 + tid);
    if (q < 2304u) {
      const unsigned row = q / 72u;            // 32 (z,y) rows of 32 voxels
      const unsigned f   = q - row * 72u;
      const int zz = z0 + (int)(row >> 3);
      const int yr = (int)(row & 7u);
      const unsigned vb = (unsigned)((zz << 14) | ((y0 + yr) << 7) | x0);
      ((float4*)out)[(size_t)(vb >> 2) * 9 + f] = tf4[row * 72 + f];
    }
  }
}

// ---------------------------------------------------------------------------
// d_in: [0] input (P floats), [1] ksigma (1 float), [2] k (int), [3] w (int)
// d_ws: unused (fully fused).
// ---------------------------------------------------------------------------
extern "C" void kernel_launch(void* const* d_in, const int* in_sizes, int n_in,
                              void* d_out, int out_size, void* d_ws, size_t ws_size,
                              hipStream_t stream) {
  const float* anat = (const float*)d_in[0];
  const float* ksig = (const float*)d_in[1];
  buildk_fused4<<<P / NCORE, 512, 0, stream>>>(anat, ksig, (float*)d_out);
}

// Round 9
// 107.209 us; speedup vs baseline: 1.1851x; 1.1851x over previous
//
#include <hip/hip_runtime.h>
#include <hip/hip_fp16.h>
#include <array>

// Problem constants (reference: H=64, M=N=128, k=9, w=3)
constexpr int HZ   = 64;
constexpr int NN   = 128;
constexpr int P    = HZ * NN * NN;    // 1,048,576 voxels
constexpr int KSEL = 9;
constexpr int NCOL = 27;              // 3x3x3 window

typedef _Float16 f16x2 __attribute__((ext_vector_type(2)));

// Fused tile geometry: core 4z x 8y x 32x = 1024 voxels per 512-thread block.
constexpr int CZ = 4, CY = 8, CX = 32;
constexpr int NCORE = CZ * CY * CX;         // 1024
constexpr int RZ = 6, RY = 10, RX = 34;     // row halo (core +1 each side)
constexpr int NROWS = RZ * RY * RX;         // 2040 sorted rows per block
constexpr int NHALO = NROWS - NCORE;        // 1016 pure-halo rows

// ---------------------------------------------------------------------------
// Batcher merge-exchange network for n=27 + backward dead-CE pruning.
// ---------------------------------------------------------------------------
constexpr int compute_nce(int n) {
  int t = 0; while ((1 << t) < n) ++t;
  int cnt = 0;
  for (int p = 1 << (t - 1); p > 0; p >>= 1) {
    int q = 1 << (t - 1), r = 0, d = p;
    while (true) {
      for (int i = 0; i < n - d; ++i)
        if ((i & p) == r) ++cnt;
      if (q == p) break;
      d = q - p; r = p; q >>= 1;
    }
  }
  return cnt;
}
constexpr int NCE_FULL = compute_nce(NCOL);   // 155

struct CEPair { unsigned char a, b; };
constexpr std::array<CEPair, NCE_FULL> make_net() {
  std::array<CEPair, NCE_FULL> net{};
  int t = 0; while ((1 << t) < NCOL) ++t;
  int k = 0;
  for (int p = 1 << (t - 1); p > 0; p >>= 1) {
    int q = 1 << (t - 1), r = 0, d = p;
    while (true) {
      for (int i = 0; i < NCOL - d; ++i)
        if ((i & p) == r) {
          net[k].a = (unsigned char)i;
          net[k].b = (unsigned char)(i + d);
          ++k;
        }
      if (q == p) break;
      d = q - p; r = p; q >>= 1;
    }
  }
  return net;
}
constexpr auto FULLNET = make_net();

constexpr int count_pruned() {
  bool needed[NCOL] = {};
  for (int i = 0; i < KSEL; ++i) needed[i] = true;
  int cnt = 0;
  for (int e = NCE_FULL - 1; e >= 0; --e) {
    const int a = FULLNET[e].a, b = FULLNET[e].b;
    if (needed[a] || needed[b]) { needed[a] = true; needed[b] = true; ++cnt; }
  }
  return cnt;
}
constexpr int NCE = count_pruned();

constexpr std::array<CEPair, NCE> make_pruned() {
  bool needed[NCOL] = {};
  for (int i = 0; i < KSEL; ++i) needed[i] = true;
  std::array<bool, NCE_FULL> keep{};
  for (int e = NCE_FULL - 1; e >= 0; --e) {
    const int a = FULLNET[e].a, b = FULLNET[e].b;
    if (needed[a] || needed[b]) { keep[e] = true; needed[a] = true; needed[b] = true; }
  }
  std::array<CEPair, NCE> out{};
  int k = 0;
  for (int e = 0; e < NCE_FULL; ++e) if (keep[e]) out[k++] = FULLNET[e];
  return out;
}
constexpr auto NET = make_pruned();

// Pure-halo row ids (rows whose col-bits nobody needs): 1016 x u16 = 2 KB.
constexpr std::array<unsigned short, NHALO> make_halo() {
  std::array<unsigned short, NHALO> t{};
  int k = 0;
  for (int r = 0; r < NROWS; ++r) {
    const int rz = r / (RY * RX), rem = r % (RY * RX);
    const int ry = rem / RX, rx = rem % RX;
    const bool core = (rz >= 1 && rz <= CZ) && (ry >= 1 && ry <= CY) &&
                      (rx >= 1 && rx <= CX);
    if (!core) t[k++] = (unsigned short)r;
  }
  return t;
}
__device__ constexpr auto HALO = make_halo();

// ---------------------------------------------------------------------------
// Per-row sort, global-read key build. Window values come straight from
// global (input = 4 MB, L2-resident per XCD; lanes read consecutive x ->
// coalesced). Index fields are disjoint (z:19..14, y:13..7, x:6..0) so
// addresses compose with OR. Center plane (czi=1) loads first.
//
// key = db<<32 | col<<27 | vbits>>5 (63 bits, sign bit 0). IEEE order ==
// unsigned order for non-negative doubles -> CE = v_min_f64 + v_max_f64
// (R7-proven: the u64 cmp+cndmask CE of R8 was 1.75x more VALU cycles).
// Order = (db, col) exactly -> exact NumPy stable order.
// ---------------------------------------------------------------------------
__device__ __forceinline__ void sort_row_g(
    const float* __restrict__ anat, int z0, int y0, int x0,
    int rz, int ry, int rx,
    unsigned od[4], unsigned& h8, unsigned& lo, unsigned& hi) {
  unsigned zp[3], yp[3], xp[3];
  #pragma unroll
  for (int j = 0; j < 3; ++j) {
    zp[j] = ((unsigned)(z0 + rz + j - 2) & (HZ - 1)) << 14;
    yp[j] = ((unsigned)(y0 + ry + j - 2) & (NN - 1)) << 7;
    xp[j] = (unsigned)(x0 + rx + j - 2) & (NN - 1);
  }

  unsigned long long key[NCOL];

  // Plane czi=1 first (contains the center at cy=1,cx=1).
  float v1[9];
  #pragma unroll
  for (int cy = 0; cy < 3; ++cy)
    #pragma unroll
    for (int cx = 0; cx < 3; ++cx)
      v1[cy * 3 + cx] = anat[zp[1] | yp[cy] | xp[cx]];
  const float center = v1[4];

  #pragma unroll
  for (int i = 0; i < 9; ++i) {
    const unsigned c = 9 + (unsigned)i;
    const unsigned vb = __float_as_uint(v1[i]);
    const unsigned db = __float_as_uint(v1[i] - center) & 0x7fffffffu;
    key[c] = ((unsigned long long)db << 32) | ((c << 27) | (vb >> 5));
  }
  // Planes czi=0 and czi=2.
  #pragma unroll
  for (int pz = 0; pz < 2; ++pz) {
    const unsigned czi = pz * 2u;              // 0 or 2
    float vp[9];
    #pragma unroll
    for (int cy = 0; cy < 3; ++cy)
      #pragma unroll
      for (int cx = 0; cx < 3; ++cx)
        vp[cy * 3 + cx] = anat[zp[czi] | yp[cy] | xp[cx]];
    #pragma unroll
    for (int i = 0; i < 9; ++i) {
      const unsigned c = czi * 9u + (unsigned)i;
      const unsigned vb = __float_as_uint(vp[i]);
      const unsigned db = __float_as_uint(vp[i] - center) & 0x7fffffffu;
      key[c] = ((unsigned long long)db << 32) | ((c << 27) | (vb >> 5));
    }
  }

  // Pruned sorting network; CE = f64 min/max pair (R7-proven encoding).
  #pragma unroll
  for (int e = 0; e < NCE; ++e) {
    const int a = NET[e].a, b = NET[e].b;
    const double ka = __builtin_bit_cast(double, key[a]);
    const double kb = __builtin_bit_cast(double, key[b]);
    key[a] = __builtin_bit_cast(unsigned long long, fmin(ka, kb));
    key[b] = __builtin_bit_cast(unsigned long long, fmax(ka, kb));
  }

  od[0] = od[1] = od[2] = od[3] = 0; h8 = 0; lo = 0; hi = 0;
  #pragma unroll
  for (int k = 0; k < KSEL; ++k) {
    const unsigned kl = (unsigned)key[k];
    const unsigned c  = (kl >> 27) & 31u;
    const unsigned vbits = (kl & 0x07ffffffu) << 5;
    const unsigned hb = (unsigned)__half_as_ushort(__float2half(__uint_as_float(vbits)));
    if (k < 8) od[k >> 1] |= hb << ((k & 1) * 16);
    else       h8 = hb;
    if (k < 6) lo |= c << (5 * k);
    else       hi |= c << (5 * (k - 6));
  }
}

// ---------------------------------------------------------------------------
// Fused kernel, rows-only LDS (36.9 KB -> 4 blocks/CU = 32 waves/CU, and
// 4 x 256 CU = 1024 blocks co-resident in ONE round -- zero dispatch tail).
//   tA  [2040 x 16B] : halves h0..h7          (gathered by neighbors)
//   tB0h[2040 x 2B]  : h8                     (gathered by neighbors)
// No input staging: key build reads L2-resident input directly.
// Own-core-row col-bits live in registers; NO launch_bounds min-occupancy
// clause (R6: capping forced the 27xu64 key array to scratch).
// ---------------------------------------------------------------------------
__global__ __launch_bounds__(512) void buildk_fused5(
    const float* __restrict__ anat,
    const float* __restrict__ ksig,
    float* __restrict__ out) {
  // rows need 36720 B; output staging needs 36864 B -> allocate the max.
  __shared__ __align__(16) unsigned char ldsb[36864];
  unsigned*       tA   = (unsigned*)ldsb;                          // 32640 B
  unsigned short* tB0h = (unsigned short*)(ldsb + NROWS * 16);     //  4080 B

  const int tid = threadIdx.x;

  // 1024 blocks = 16 zt x 16 yt x 4 xt tiles; XCD-aware bijective swizzle.
  const int blk = blockIdx.x;
  const int swz = ((blk & 7) << 7) | (blk >> 3);
  const int zt   = swz >> 6;
  const int rest = swz & 63;
  const int y0   = ((rest >> 2) & 15) << 3;
  const int x0   = (rest & 3) << 5;
  const int z0   = zt << 2;

  const int xl = tid & 31;
  const int yl = (tid >> 5) & 7;
  const int zl = tid >> 8;                    // 0..1

  // ---- Sort phase: 2 own core rows (straight-line) + 1016 halo rows ----
  unsigned lo0, hi0, lo1, hi1;
  {
    unsigned od[4], h8;
    const int rz = 2 * zl + 1, ry = yl + 1, rx = xl + 1;
    const int ru = (rz * RY + ry) * RX + rx;
    sort_row_g(anat, z0, y0, x0, rz, ry, rx, od, h8, lo0, hi0);
    *(uint4*)&tA[(unsigned)ru * 4] = make_uint4(od[0], od[1], od[2], od[3]);
    tB0h[ru] = (unsigned short)h8;
  }
  {
    unsigned od[4], h8;
    const int rz = 2 * zl + 2, ry = yl + 1, rx = xl + 1;
    const int ru = (rz * RY + ry) * RX + rx;
    sort_row_g(anat, z0, y0, x0, rz, ry, rx, od, h8, lo1, hi1);
    *(uint4*)&tA[(unsigned)ru * 4] = make_uint4(od[0], od[1], od[2], od[3]);
    tB0h[ru] = (unsigned short)h8;
  }
  #pragma unroll 1
  for (int s = 0; s < 2; ++s) {
    const int idx = s * 512 + tid;
    if (idx < NHALO) {
      const int ru = (int)HALO[idx];
      const int rz = ru / (RY * RX);
      const int rem = ru - (RY * RX) * rz;
      const int ry = rem / RX, rx = rem - RX * ry;
      unsigned od[4], h8, lo, hi;
      sort_row_g(anat, z0, y0, x0, rz, ry, rx, od, h8, lo, hi);
      *(uint4*)&tA[(unsigned)ru * 4] = make_uint4(od[0], od[1], od[2], od[3]);
      tB0h[ru] = (unsigned short)h8;
    }
  }
  __syncthreads();

  // ---- Weights phase: 2 core voxels per thread ----
  const float ks = ksig[0];
  const _Float16 epsh = (_Float16)1e-6f;
  const f16x2 eps2 = {epsh, epsh};

  float res[2][9];

  #pragma unroll
  for (int vz = 0; vz < 2; ++vz) {
    const int zv = 2 * zl + vz;               // core z offset 0..3
    const unsigned lo = (vz == 0) ? lo0 : lo1;
    const unsigned hi = (vz == 0) ? hi0 : hi1;

    const int rho_own = ((zv + 1) * RY + (yl + 1)) * RX + (xl + 1);
    const uint4 a = *(const uint4*)&tA[rho_own * 4];
    const unsigned b0 = (unsigned)tB0h[rho_own];
    f16x2 wh[5];
    wh[0] = __builtin_bit_cast(f16x2, a.x);
    wh[1] = __builtin_bit_cast(f16x2, a.y);
    wh[2] = __builtin_bit_cast(f16x2, a.z);
    wh[3] = __builtin_bit_cast(f16x2, a.w);
    wh[4] = __builtin_bit_cast(f16x2, b0);    // hi half = 0 pad

    // Decode all 9 neighbor row addresses, then batch-issue all 18 reads.
    int rho[KSEL];
    #pragma unroll
    for (int j = 0; j < KSEL; ++j) {
      const unsigned c = (j < 6) ? ((lo >> (5 * j)) & 31u)
                                 : ((hi >> (5 * (j - 6))) & 31u);
      const unsigned czi = (c * 57u) >> 9;
      const unsigned rem = c - 9u * czi;
      const unsigned cyi = (rem * 11u) >> 5;
      const unsigned cxi = rem - 3u * cyi;
      rho[j] = ((zv + (int)czi) * RY + (yl + (int)cyi)) * RX + (xl + (int)cxi);
    }
    uint4 na[KSEL];
    unsigned nb[KSEL];
    #pragma unroll
    for (int j = 0; j < KSEL; ++j) {
      na[j] = *(const uint4*)&tA[rho[j] * 4];
      nb[j] = (unsigned)tB0h[rho[j]];
    }

    // sigma with ddof=1 (two-pass, matches jnp.std).
    float ws[KSEL];
    #pragma unroll
    for (int l = 0; l < KSEL; ++l) ws[l] = (float)wh[l >> 1][l & 1];
    float mean = 0.f;
    #pragma unroll
    for (int l = 0; l < KSEL; ++l) mean += ws[l];
    mean *= (1.0f / 9.0f);
    float var = 0.f;
    #pragma unroll
    for (int l = 0; l < KSEL; ++l) { const float t = ws[l] - mean; var += t * t; }
    var *= (1.0f / 8.0f);
    const float sigma = sqrtf(var);

    // log2(e) folded in: e[j] = exp2(logit[j] - mx)
    const float inv2 = (sigma == 0.f)
        ? 0.f
        : 1.4426950408889634f / (2.0f * ks * ks * sigma * sigma);

    float logit[KSEL];
    #pragma unroll
    for (int j = 0; j < KSEL; ++j) {
      const f16x2 nh0 = __builtin_bit_cast(f16x2, na[j].x);
      const f16x2 nh1 = __builtin_bit_cast(f16x2, na[j].y);
      const f16x2 nh2 = __builtin_bit_cast(f16x2, na[j].z);
      const f16x2 nh3 = __builtin_bit_cast(f16x2, na[j].w);
      const f16x2 nh4 = __builtin_bit_cast(f16x2, nb[j]);
      float s = 0.f;
      f16x2 dd;
      dd = (wh[0] - nh0) + eps2; s = __builtin_amdgcn_fdot2(dd, dd, s, false);
      dd = (wh[1] - nh1) + eps2; s = __builtin_amdgcn_fdot2(dd, dd, s, false);
      dd = (wh[2] - nh2) + eps2; s = __builtin_amdgcn_fdot2(dd, dd, s, false);
      dd = (wh[3] - nh3) + eps2; s = __builtin_amdgcn_fdot2(dd, dd, s, false);
      dd = (wh[4] - nh4) + eps2; s = __builtin_amdgcn_fdot2(dd, dd, s, false);
      logit[j] = -s * inv2;
    }

    // softmax (exp2 domain) over the 9 logits
    float mx = logit[0];
    #pragma unroll
    for (int j = 1; j < KSEL; ++j) mx = fmaxf(mx, logit[j]);
    float sum = 0.f;
    float e[KSEL];
    #pragma unroll
    for (int j = 0; j < KSEL; ++j) { e[j] = exp2f(logit[j] - mx); sum += e[j]; }
    const float rs = 1.0f / sum;
    #pragma unroll
    for (int j = 0; j < KSEL; ++j) res[vz][j] = e[j] * rs;
  }

  // ---- Output staging through LDS -> coalesced float4 stores ----
  __syncthreads();                            // rows LDS now dead
  float* tf = (float*)ldsb;                   // 36864 B exactly
  #pragma unroll
  for (int vz = 0; vz < 2; ++vz) {
    const int zv = 2 * zl + vz;
    const int pos = (zv << 8) + (yl << 5) + xl;   // zv-major staging order
    #pragma unroll
    for (int j = 0; j < KSEL; ++j) tf[pos * KSEL + j] = res[vz][j];
  }
  __syncthreads();

  const float4* tf4 = (const float4*)ldsb;
  #pragma unroll
  for (int s = 0; s < 5; ++s) {
    const unsigned q = (unsigned)(s * 512 + tid);
    if (q < 2304u) {
      const unsigned row = q / 72u;            // 32 (z,y) rows of 32 voxels
      const unsigned f   = q - row * 72u;
      const int zz = z0 + (int)(row >> 3);
      const int yr = (int)(row & 7u);
      const unsigned vb = (unsigned)((zz << 14) | ((y0 + yr) << 7) | x0);
      ((float4*)out)[(size_t)(vb >> 2) * 9 + f] = tf4[row * 72 + f];
    }
  }
}

// ---------------------------------------------------------------------------
// d_in: [0] input (P floats), [1] ksigma (1 float), [2] k (int), [3] w (int)
// d_ws: unused (fully fused).
// ---------------------------------------------------------------------------
extern "C" void kernel_launch(void* const* d_in, const int* in_sizes, int n_in,
                              void* d_out, int out_size, void* d_ws, size_t ws_size,
                              hipStream_t stream) {
  const float* anat = (const float*)d_in[0];
  const float* ksig = (const float*)d_in[1];
  buildk_fused5<<<P / NCORE, 512, 0, stream>>>(anat, ksig, (float*)d_out);
}

// Round 10
// 103.080 us; speedup vs baseline: 1.2325x; 1.0401x over previous
//
#include <hip/hip_runtime.h>
#include <hip/hip_fp16.h>
#include <array>

// Problem constants (reference: H=64, M=N=128, k=9, w=3)
constexpr int HZ   = 64;
constexpr int NN   = 128;
constexpr int P    = HZ * NN * NN;    // 1,048,576 voxels
constexpr int KSEL = 9;
constexpr int NCOL = 27;              // 3x3x3 window

typedef _Float16 f16x2 __attribute__((ext_vector_type(2)));

// Fused tile geometry: core 8z x 8y x 16x = 1024 voxels per 512-thread block.
// Halo rows 10x10x18 = 1800 (1.76x redundancy, was 2040 / 1.99x at 4x8x32).
constexpr int CZ = 8, CY = 8, CX = 16;
constexpr int NCORE = CZ * CY * CX;         // 1024
constexpr int RZ = 10, RY = 10, RX = 18;    // row halo (core +1 each side)
constexpr int NROWS = RZ * RY * RX;         // 1800 sorted rows per block
constexpr int NHALO = NROWS - NCORE;        // 776 pure-halo rows
constexpr int IZ = 12, IY = 12, IXW = 24;   // input halo (row halo +1, x 16B-aligned)
constexpr int NIN = IZ * IY * IXW;          // 3456 floats
constexpr int NIN16 = IZ * IY * (IXW / 4);  // 864 16-byte staging groups

// ---------------------------------------------------------------------------
// Batcher merge-exchange network for n=27 + backward dead-CE pruning.
// ---------------------------------------------------------------------------
constexpr int compute_nce(int n) {
  int t = 0; while ((1 << t) < n) ++t;
  int cnt = 0;
  for (int p = 1 << (t - 1); p > 0; p >>= 1) {
    int q = 1 << (t - 1), r = 0, d = p;
    while (true) {
      for (int i = 0; i < n - d; ++i)
        if ((i & p) == r) ++cnt;
      if (q == p) break;
      d = q - p; r = p; q >>= 1;
    }
  }
  return cnt;
}
constexpr int NCE_FULL = compute_nce(NCOL);   // 155

struct CEPair { unsigned char a, b; };
constexpr std::array<CEPair, NCE_FULL> make_net() {
  std::array<CEPair, NCE_FULL> net{};
  int t = 0; while ((1 << t) < NCOL) ++t;
  int k = 0;
  for (int p = 1 << (t - 1); p > 0; p >>= 1) {
    int q = 1 << (t - 1), r = 0, d = p;
    while (true) {
      for (int i = 0; i < NCOL - d; ++i)
        if ((i & p) == r) {
          net[k].a = (unsigned char)i;
          net[k].b = (unsigned char)(i + d);
          ++k;
        }
      if (q == p) break;
      d = q - p; r = p; q >>= 1;
    }
  }
  return net;
}
constexpr auto FULLNET = make_net();

constexpr int count_pruned() {
  bool needed[NCOL] = {};
  for (int i = 0; i < KSEL; ++i) needed[i] = true;
  int cnt = 0;
  for (int e = NCE_FULL - 1; e >= 0; --e) {
    const int a = FULLNET[e].a, b = FULLNET[e].b;
    if (needed[a] || needed[b]) { needed[a] = true; needed[b] = true; ++cnt; }
  }
  return cnt;
}
constexpr int NCE = count_pruned();

constexpr std::array<CEPair, NCE> make_pruned() {
  bool needed[NCOL] = {};
  for (int i = 0; i < KSEL; ++i) needed[i] = true;
  std::array<bool, NCE_FULL> keep{};
  for (int e = NCE_FULL - 1; e >= 0; --e) {
    const int a = FULLNET[e].a, b = FULLNET[e].b;
    if (needed[a] || needed[b]) { keep[e] = true; needed[a] = true; needed[b] = true; }
  }
  std::array<CEPair, NCE> out{};
  int k = 0;
  for (int e = 0; e < NCE_FULL; ++e) if (keep[e]) out[k++] = FULLNET[e];
  return out;
}
constexpr auto NET = make_pruned();

// Pure-halo row ids (rows whose col-bits nobody needs): 776 x u16.
constexpr std::array<unsigned short, NHALO> make_halo() {
  std::array<unsigned short, NHALO> t{};
  int k = 0;
  for (int r = 0; r < NROWS; ++r) {
    const int rz = r / (RY * RX), rem = r % (RY * RX);
    const int ry = rem / RX, rx = rem % RX;
    const bool core = (rz >= 1 && rz <= CZ) && (ry >= 1 && ry <= CY) &&
                      (rx >= 1 && rx <= CX);
    if (!core) t[k++] = (unsigned short)r;
  }
  return t;
}
__device__ constexpr auto HALO = make_halo();

// ---------------------------------------------------------------------------
// Async global->LDS DMA helper (16 B wide, lane-linear dest).
// ---------------------------------------------------------------------------
typedef const __attribute__((address_space(1))) unsigned GU;
typedef __attribute__((address_space(3))) unsigned LU;

__device__ __forceinline__ void g2l16(const void* g, void* l) {
  __builtin_amdgcn_global_load_lds((GU*)g, (LU*)l, 16, 0, 0);
}

// ---------------------------------------------------------------------------
// Per-row sort: key = db<<32 | col<<27 | vbits>>5 (63 bits, sign bit 0).
// IEEE order == unsigned order for non-negative doubles -> CE = v_min_f64 +
// v_max_f64: two INDEPENDENT DP ops per CE -- empirically the cheapest 64-bit
// CE on gfx950 (R8: u64 cmp+4xcndmask was 1.75x more VALU cycles due to the
// vcc write->read chain). Order = (db, col) -> exact NumPy stable order.
// COLS=false (halo rows): skip the dead col-bit packing.
// ---------------------------------------------------------------------------
template <bool COLS>
__device__ __forceinline__ void sort_row(
    const float* __restrict__ in_t, int rz, int ry, int rx,
    unsigned od[4], unsigned& h8, unsigned& lo, unsigned& hi) {
  const float center = in_t[((rz + 1) * IY + (ry + 1)) * IXW + rx + 3];

  unsigned long long key[NCOL];
  #pragma unroll
  for (int c = 0; c < NCOL; ++c) {
    const int czi = c / 9, cyi = (c / 3) % 3, cxi = c % 3;
    const float v = in_t[((rz + czi) * IY + (ry + cyi)) * IXW + rx + cxi + 2];
    const unsigned vb = __float_as_uint(v);
    const unsigned db = __float_as_uint(v - center) & 0x7fffffffu;
    key[c] = ((unsigned long long)db << 32) |
             (((unsigned)c << 27) | (vb >> 5));
  }

  #pragma unroll
  for (int e = 0; e < NCE; ++e) {
    const int a = NET[e].a, b = NET[e].b;
    const double ka = __builtin_bit_cast(double, key[a]);
    const double kb = __builtin_bit_cast(double, key[b]);
    key[a] = __builtin_bit_cast(unsigned long long, fmin(ka, kb));
    key[b] = __builtin_bit_cast(unsigned long long, fmax(ka, kb));
  }

  od[0] = od[1] = od[2] = od[3] = 0; h8 = 0; lo = 0; hi = 0;
  #pragma unroll
  for (int k = 0; k < KSEL; ++k) {
    const unsigned kl = (unsigned)key[k];
    const unsigned vbits = (kl & 0x07ffffffu) << 5;
    const unsigned hb = (unsigned)__half_as_ushort(__float2half(__uint_as_float(vbits)));
    if (k < 8) od[k >> 1] |= hb << ((k & 1) * 16);
    else       h8 = hb;
    if (COLS) {
      const unsigned c = (kl >> 27) & 31u;
      if (k < 6) lo |= c << (5 * k);
      else       hi |= c << (5 * (k - 6));
    }
  }
}

// ---------------------------------------------------------------------------
// Fused kernel, 8x8x16 tile (R7-proven structure, lower halo redundancy).
//   tA  [1800 x 16B] : halves h0..h7          (gathered by neighbors)
//   tB0h[1800 x 2B]  : h8                     (gathered by neighbors)
//   in_t[3456 x 4B]  : input halo
// Total 46224 B -> 3 blocks/CU. Own-core-row col-bits live in registers;
// sort phase straight-line (two explicit own-row sorts + rolled halo loop).
// NO launch_bounds min-occupancy clause (R6: capping spilled the key array).
// ---------------------------------------------------------------------------
__global__ __launch_bounds__(512) void buildk_fused6(
    const float* __restrict__ anat,
    const float* __restrict__ ksig,
    float* __restrict__ out) {
  __shared__ __align__(16) unsigned char ldsb[NROWS * 16 + NROWS * 2 + NIN * 4];
  unsigned*       tA   = (unsigned*)ldsb;                          // 28800 B
  unsigned short* tB0h = (unsigned short*)(ldsb + NROWS * 16);     //  3600 B
  float*          in_t = (float*)(ldsb + NROWS * 16 + NROWS * 2);  // 13824 B

  const int tid = threadIdx.x;

  // 1024 blocks = 8 zt x 16 yt x 8 xt tiles; XCD-aware bijective swizzle:
  // XCD k owns zt = k (z-slab of 8) -> input slab + gathers stay L2-local.
  const int blk = blockIdx.x;
  const int swz = ((blk & 7) << 7) | (blk >> 3);
  const int zt   = swz >> 7;                  // 0..7
  const int rest = swz & 127;
  const int y0   = ((rest >> 3) & 15) << 3;
  const int x0   = (rest & 7) << 4;
  const int z0   = zt << 3;

  const int xl = tid & 15;                    // 0..15
  const int yl = (tid >> 4) & 7;              // 0..7
  const int zl = tid >> 7;                    // 0..3

  // ---- Stage input halo: 864 x 16B lane-linear DMA ----
  #pragma unroll
  for (int s = 0; s < 2; ++s) {
    const unsigned q = (unsigned)(s * 512 + tid);
    if (q < (unsigned)NIN16) {
      const unsigned p = q / 6u;               // plane-row 0..143
      const unsigned t = q - 6u * p;           // 16B group 0..5
      const unsigned iz = p / 12u;
      const unsigned iy = p - 12u * iz;
      const int zz = (z0 + (int)iz - 2) & (HZ - 1);
      const int yy = (y0 + (int)iy - 2) & (NN - 1);
      const int xb = (x0 - 4 + 4 * (int)t) & (NN - 1);
      g2l16(&anat[(zz << 14) | (yy << 7) | xb], &in_t[q * 4]);
    }
  }
  __syncthreads();

  // ---- Sort phase: 2 own core rows (straight-line) + 776 halo rows ----
  unsigned lo0, hi0, lo1, hi1;
  {
    unsigned od[4], h8;
    const int rz = 2 * zl + 1, ry = yl + 1, rx = xl + 1;
    const int ru = (rz * RY + ry) * RX + rx;
    sort_row<true>(in_t, rz, ry, rx, od, h8, lo0, hi0);
    *(uint4*)&tA[(unsigned)ru * 4] = make_uint4(od[0], od[1], od[2], od[3]);
    tB0h[ru] = (unsigned short)h8;
  }
  {
    unsigned od[4], h8;
    const int rz = 2 * zl + 2, ry = yl + 1, rx = xl + 1;
    const int ru = (rz * RY + ry) * RX + rx;
    sort_row<true>(in_t, rz, ry, rx, od, h8, lo1, hi1);
    *(uint4*)&tA[(unsigned)ru * 4] = make_uint4(od[0], od[1], od[2], od[3]);
    tB0h[ru] = (unsigned short)h8;
  }
  #pragma unroll 1
  for (int s = 0; s < 2; ++s) {
    const int idx = s * 512 + tid;
    if (idx < NHALO) {
      const int ru = (int)HALO[idx];
      const int rz = ru / (RY * RX);
      const int rem = ru - (RY * RX) * rz;
      const int ry = rem / RX, rx = rem - RX * ry;
      unsigned od[4], h8, lo, hi;
      sort_row<false>(in_t, rz, ry, rx, od, h8, lo, hi);
      *(uint4*)&tA[(unsigned)ru * 4] = make_uint4(od[0], od[1], od[2], od[3]);
      tB0h[ru] = (unsigned short)h8;
    }
  }
  __syncthreads();

  // ---- Weights phase: 2 core voxels per thread ----
  const float ks = ksig[0];
  const _Float16 epsh = (_Float16)1e-6f;
  const f16x2 eps2 = {epsh, epsh};

  float res[2][9];

  #pragma unroll
  for (int vz = 0; vz < 2; ++vz) {
    const int zv = 2 * zl + vz;               // core z offset 0..7
    const unsigned lo = (vz == 0) ? lo0 : lo1;
    const unsigned hi = (vz == 0) ? hi0 : hi1;

    const int rho_own = ((zv + 1) * RY + (yl + 1)) * RX + (xl + 1);
    const uint4 a = *(const uint4*)&tA[rho_own * 4];
    const unsigned b0 = (unsigned)tB0h[rho_own];
    f16x2 wh[5];
    wh[0] = __builtin_bit_cast(f16x2, a.x);
    wh[1] = __builtin_bit_cast(f16x2, a.y);
    wh[2] = __builtin_bit_cast(f16x2, a.z);
    wh[3] = __builtin_bit_cast(f16x2, a.w);
    wh[4] = __builtin_bit_cast(f16x2, b0);    // hi half = 0 pad

    // Decode all 9 neighbor row addresses, then batch-issue all 18 reads.
    int rho[KSEL];
    #pragma unroll
    for (int j = 0; j < KSEL; ++j) {
      const unsigned c = (j < 6) ? ((lo >> (5 * j)) & 31u)
                                 : ((hi >> (5 * (j - 6))) & 31u);
      const unsigned czi = (c * 57u) >> 9;
      const unsigned rem = c - 9u * czi;
      const unsigned cyi = (rem * 11u) >> 5;
      const unsigned cxi = rem - 3u * cyi;
      rho[j] = ((zv + (int)czi) * RY + (yl + (int)cyi)) * RX + (xl + (int)cxi);
    }
    uint4 na[KSEL];
    unsigned nb[KSEL];
    #pragma unroll
    for (int j = 0; j < KSEL; ++j) {
      na[j] = *(const uint4*)&tA[rho[j] * 4];
      nb[j] = (unsigned)tB0h[rho[j]];
    }

    // sigma with ddof=1 (two-pass, matches jnp.std).
    float ws[KSEL];
    #pragma unroll
    for (int l = 0; l < KSEL; ++l) ws[l] = (float)wh[l >> 1][l & 1];
    float mean = 0.f;
    #pragma unroll
    for (int l = 0; l < KSEL; ++l) mean += ws[l];
    mean *= (1.0f / 9.0f);
    float var = 0.f;
    #pragma unroll
    for (int l = 0; l < KSEL; ++l) { const float t = ws[l] - mean; var += t * t; }
    var *= (1.0f / 8.0f);
    const float sigma = sqrtf(var);

    // log2(e) folded in: e[j] = exp2(logit[j] - mx)
    const float inv2 = (sigma == 0.f)
        ? 0.f
        : 1.4426950408889634f / (2.0f * ks * ks * sigma * sigma);

    float logit[KSEL];
    #pragma unroll
    for (int j = 0; j < KSEL; ++j) {
      const f16x2 nh0 = __builtin_bit_cast(f16x2, na[j].x);
      const f16x2 nh1 = __builtin_bit_cast(f16x2, na[j].y);
      const f16x2 nh2 = __builtin_bit_cast(f16x2, na[j].z);
      const f16x2 nh3 = __builtin_bit_cast(f16x2, na[j].w);
      const f16x2 nh4 = __builtin_bit_cast(f16x2, nb[j]);
      float s = 0.f;
      f16x2 dd;
      dd = (wh[0] - nh0) + eps2; s = __builtin_amdgcn_fdot2(dd, dd, s, false);
      dd = (wh[1] - nh1) + eps2; s = __builtin_amdgcn_fdot2(dd, dd, s, false);
      dd = (wh[2] - nh2) + eps2; s = __builtin_amdgcn_fdot2(dd, dd, s, false);
      dd = (wh[3] - nh3) + eps2; s = __builtin_amdgcn_fdot2(dd, dd, s, false);
      dd = (wh[4] - nh4) + eps2; s = __builtin_amdgcn_fdot2(dd, dd, s, false);
      logit[j] = -s * inv2;
    }

    // softmax (exp2 domain) over the 9 logits
    float mx = logit[0];
    #pragma unroll
    for (int j = 1; j < KSEL; ++j) mx = fmaxf(mx, logit[j]);
    float sum = 0.f;
    float e[KSEL];
    #pragma unroll
    for (int j = 0; j < KSEL; ++j) { e[j] = exp2f(logit[j] - mx); sum += e[j]; }
    const float rs = 1.0f / sum;
    #pragma unroll
    for (int j = 0; j < KSEL; ++j) res[vz][j] = e[j] * rs;
  }

  // ---- Output staging through LDS -> coalesced float4 stores ----
  __syncthreads();                            // rows LDS now dead
  float* tf = (float*)ldsb;                   // 36864 B < 46224 B total
  #pragma unroll
  for (int vz = 0; vz < 2; ++vz) {
    const int zv = 2 * zl + vz;
    const int pos = (zv << 7) + (yl << 4) + xl;   // zv-major staging order
    #pragma unroll
    for (int j = 0; j < KSEL; ++j) tf[pos * KSEL + j] = res[vz][j];
  }
  __syncthreads();

  const float4* tf4 = (const float4*)ldsb;
  #pragma unroll
  for (int s = 0; s < 5; ++s) {
    const unsigned q = (unsigned)(s * 512 + tid);
    if (q < 2304u) {
      const unsigned row = q / 36u;            // 64 (z,y) rows of 16 voxels
      const unsigned f   = q - row * 36u;
      const int zz = z0 + (int)(row >> 3);
      const int yr = (int)(row & 7u);
      const unsigned vb = (unsigned)((zz << 14) | ((y0 + yr) << 7) | x0);
      ((float4*)out)[(size_t)(vb >> 2) * 9 + f] = tf4[row * 36 + f];
    }
  }
}

// ---------------------------------------------------------------------------
// d_in: [0] input (P floats), [1] ksigma (1 float), [2] k (int), [3] w (int)
// d_ws: unused (fully fused).
// ---------------------------------------------------------------------------
extern "C" void kernel_launch(void* const* d_in, const int* in_sizes, int n_in,
                              void* d_out, int out_size, void* d_ws, size_t ws_size,
                              hipStream_t stream) {
  const float* anat = (const float*)d_in[0];
  const float* ksig = (const float*)d_in[1];
  buildk_fused6<<<P / NCORE, 512, 0, stream>>>(anat, ksig, (float*)d_out);
}

// Round 11
// 101.624 us; speedup vs baseline: 1.2502x; 1.0143x over previous
//
#include <hip/hip_runtime.h>
#include <hip/hip_fp16.h>
#include <array>

// Problem constants (reference: H=64, M=N=128, k=9, w=3)
constexpr int HZ   = 64;
constexpr int NN   = 128;
constexpr int P    = HZ * NN * NN;    // 1,048,576 voxels
constexpr int KSEL = 9;
constexpr int NCOL = 27;              // 3x3x3 window

typedef _Float16 f16x2 __attribute__((ext_vector_type(2)));

// Fused tile geometry: core 8z x 8y x 16x = 1024 voxels per 512-thread block.
// Halo rows 10x10x18 = 1800 (1.76x redundancy).
constexpr int CZ = 8, CY = 8, CX = 16;
constexpr int NCORE = CZ * CY * CX;         // 1024
constexpr int RZ = 10, RY = 10, RX = 18;    // row halo (core +1 each side)
constexpr int NROWS = RZ * RY * RX;         // 1800 sorted rows per block
constexpr int NHALO = NROWS - NCORE;        // 776 pure-halo rows
constexpr int IZ = 12, IY = 12, IXW = 24;   // input halo (row halo +1, x 16B-aligned)
constexpr int NIN = IZ * IY * IXW;          // 3456 floats
constexpr int NIN16 = IZ * IY * (IXW / 4);  // 864 16-byte staging groups

// ---------------------------------------------------------------------------
// Batcher merge-exchange network for n=27 + backward dead-CE pruning.
// ---------------------------------------------------------------------------
constexpr int compute_nce(int n) {
  int t = 0; while ((1 << t) < n) ++t;
  int cnt = 0;
  for (int p = 1 << (t - 1); p > 0; p >>= 1) {
    int q = 1 << (t - 1), r = 0, d = p;
    while (true) {
      for (int i = 0; i < n - d; ++i)
        if ((i & p) == r) ++cnt;
      if (q == p) break;
      d = q - p; r = p; q >>= 1;
    }
  }
  return cnt;
}
constexpr int NCE_FULL = compute_nce(NCOL);   // 155

struct CEPair { unsigned char a, b; };
constexpr std::array<CEPair, NCE_FULL> make_net() {
  std::array<CEPair, NCE_FULL> net{};
  int t = 0; while ((1 << t) < NCOL) ++t;
  int k = 0;
  for (int p = 1 << (t - 1); p > 0; p >>= 1) {
    int q = 1 << (t - 1), r = 0, d = p;
    while (true) {
      for (int i = 0; i < NCOL - d; ++i)
        if ((i & p) == r) {
          net[k].a = (unsigned char)i;
          net[k].b = (unsigned char)(i + d);
          ++k;
        }
      if (q == p) break;
      d = q - p; r = p; q >>= 1;
    }
  }
  return net;
}
constexpr auto FULLNET = make_net();

constexpr int count_pruned() {
  bool needed[NCOL] = {};
  for (int i = 0; i < KSEL; ++i) needed[i] = true;
  int cnt = 0;
  for (int e = NCE_FULL - 1; e >= 0; --e) {
    const int a = FULLNET[e].a, b = FULLNET[e].b;
    if (needed[a] || needed[b]) { needed[a] = true; needed[b] = true; ++cnt; }
  }
  return cnt;
}
constexpr int NCE = count_pruned();

constexpr std::array<CEPair, NCE> make_pruned() {
  bool needed[NCOL] = {};
  for (int i = 0; i < KSEL; ++i) needed[i] = true;
  std::array<bool, NCE_FULL> keep{};
  for (int e = NCE_FULL - 1; e >= 0; --e) {
    const int a = FULLNET[e].a, b = FULLNET[e].b;
    if (needed[a] || needed[b]) { keep[e] = true; needed[a] = true; needed[b] = true; }
  }
  std::array<CEPair, NCE> out{};
  int k = 0;
  for (int e = 0; e < NCE_FULL; ++e) if (keep[e]) out[k++] = FULLNET[e];
  return out;
}
constexpr auto NET = make_pruned();

// Pure-halo row ids (rows whose col-bits nobody needs): 776 x u16.
constexpr std::array<unsigned short, NHALO> make_halo() {
  std::array<unsigned short, NHALO> t{};
  int k = 0;
  for (int r = 0; r < NROWS; ++r) {
    const int rz = r / (RY * RX), rem = r % (RY * RX);
    const int ry = rem / RX, rx = rem % RX;
    const bool core = (rz >= 1 && rz <= CZ) && (ry >= 1 && ry <= CY) &&
                      (rx >= 1 && rx <= CX);
    if (!core) t[k++] = (unsigned short)r;
  }
  return t;
}
__device__ constexpr auto HALO = make_halo();

// ---------------------------------------------------------------------------
// Async global->LDS DMA helper (16 B wide, lane-linear dest).
// ---------------------------------------------------------------------------
typedef const __attribute__((address_space(1))) unsigned GU;
typedef __attribute__((address_space(3))) unsigned LU;

__device__ __forceinline__ void g2l16(const void* g, void* l) {
  __builtin_amdgcn_global_load_lds((GU*)g, (LU*)l, 16, 0, 0);
}

// ---------------------------------------------------------------------------
// Per-row sort: key = db<<32 | col<<27 | vbits>>5 (63 bits, sign bit 0).
// IEEE order == unsigned order for non-negative doubles -> CE = v_min_f64 +
// v_max_f64 (empirically the cheapest 64-bit CE on gfx950; R8's u64
// cmp+cndmask chain was 1.75x more VALU cycles). Order = (db, col) ->
// exact NumPy stable order. Window values are loaded per-plane into
// registers FIRST (load cluster), then keys built -- lets the scheduler
// hide lgkmcnt under ALU. COLS=false (halo rows): skip dead col packing.
// ---------------------------------------------------------------------------
template <bool COLS>
__device__ __forceinline__ void sort_row(
    const float* __restrict__ in_t, int rz, int ry, int rx,
    unsigned od[4], unsigned& h8, unsigned& lo, unsigned& hi) {
  const int base = (rz * IY + ry) * IXW + rx + 2;

  unsigned long long key[NCOL];

  // Center plane (czi=1) first -- contains the center at (cy=1,cx=1).
  float v1[9];
  #pragma unroll
  for (int cy = 0; cy < 3; ++cy)
    #pragma unroll
    for (int cx = 0; cx < 3; ++cx)
      v1[cy * 3 + cx] = in_t[base + (IY + cy) * IXW + cx];
  const float center = v1[4];

  #pragma unroll
  for (int i = 0; i < 9; ++i) {
    const unsigned c = 9u + (unsigned)i;
    const unsigned vb = __float_as_uint(v1[i]);
    const unsigned db = __float_as_uint(v1[i] - center) & 0x7fffffffu;
    key[c] = ((unsigned long long)db << 32) | ((c << 27) | (vb >> 5));
  }
  // Planes czi=0 and czi=2.
  #pragma unroll
  for (int pz = 0; pz < 2; ++pz) {
    const int czi = pz * 2;                   // 0 or 2
    float vp[9];
    #pragma unroll
    for (int cy = 0; cy < 3; ++cy)
      #pragma unroll
      for (int cx = 0; cx < 3; ++cx)
        vp[cy * 3 + cx] = in_t[base + (czi * IY + cy) * IXW + cx];
    #pragma unroll
    for (int i = 0; i < 9; ++i) {
      const unsigned c = (unsigned)(czi * 9 + i);
      const unsigned vb = __float_as_uint(vp[i]);
      const unsigned db = __float_as_uint(vp[i] - center) & 0x7fffffffu;
      key[c] = ((unsigned long long)db << 32) | ((c << 27) | (vb >> 5));
    }
  }

  // Pruned sorting network; CE = f64 min/max pair.
  #pragma unroll
  for (int e = 0; e < NCE; ++e) {
    const int a = NET[e].a, b = NET[e].b;
    const double ka = __builtin_bit_cast(double, key[a]);
    const double kb = __builtin_bit_cast(double, key[b]);
    key[a] = __builtin_bit_cast(unsigned long long, fmin(ka, kb));
    key[b] = __builtin_bit_cast(unsigned long long, fmax(ka, kb));
  }

  od[0] = od[1] = od[2] = od[3] = 0; h8 = 0; lo = 0; hi = 0;
  #pragma unroll
  for (int k = 0; k < KSEL; ++k) {
    const unsigned kl = (unsigned)key[k];
    const unsigned vbits = (kl & 0x07ffffffu) << 5;
    const unsigned hb = (unsigned)__half_as_ushort(__float2half(__uint_as_float(vbits)));
    if (k < 8) od[k >> 1] |= hb << ((k & 1) * 16);
    else       h8 = hb;
    if (COLS) {
      const unsigned c = (kl >> 27) & 31u;
      if (k < 6) lo |= c << (5 * k);
      else       hi |= c << (5 * (k - 6));
    }
  }
}

// ---------------------------------------------------------------------------
// Fused kernel, 8x8x16 tile; direct output stores (no LDS staging, -2 barriers).
//   tA  [1800 x 16B] : halves h0..h7          (gathered by neighbors)
//   tB0h[1800 x 2B]  : h8                     (gathered by neighbors)
//   in_t[3456 x 4B]  : input halo
// Total 46224 B -> 3 blocks/CU. Own-core-row col-bits live in registers;
// sort phase straight-line (two explicit own-row sorts + rolled halo loop).
// NO launch_bounds min-occupancy clause (R6: capping spilled the key array).
// ---------------------------------------------------------------------------
__global__ __launch_bounds__(512) void buildk_fused7(
    const float* __restrict__ anat,
    const float* __restrict__ ksig,
    float* __restrict__ out) {
  __shared__ __align__(16) unsigned char ldsb[NROWS * 16 + NROWS * 2 + NIN * 4];
  unsigned*       tA   = (unsigned*)ldsb;                          // 28800 B
  unsigned short* tB0h = (unsigned short*)(ldsb + NROWS * 16);     //  3600 B
  float*          in_t = (float*)(ldsb + NROWS * 16 + NROWS * 2);  // 13824 B

  const int tid = threadIdx.x;

  // 1024 blocks = 8 zt x 16 yt x 8 xt tiles; XCD-aware bijective swizzle:
  // XCD k owns zt = k (z-slab of 8) -> input slab + gathers stay L2-local.
  const int blk = blockIdx.x;
  const int swz = ((blk & 7) << 7) | (blk >> 3);
  const int zt   = swz >> 7;                  // 0..7
  const int rest = swz & 127;
  const int y0   = ((rest >> 3) & 15) << 3;
  const int x0   = (rest & 7) << 4;
  const int z0   = zt << 3;

  const int xl = tid & 15;                    // 0..15
  const int yl = (tid >> 4) & 7;              // 0..7
  const int zl = tid >> 7;                    // 0..3

  // ---- Stage input halo: 864 x 16B lane-linear DMA ----
  #pragma unroll
  for (int s = 0; s < 2; ++s) {
    const unsigned q = (unsigned)(s * 512 + tid);
    if (q < (unsigned)NIN16) {
      const unsigned p = q / 6u;               // plane-row 0..143
      const unsigned t = q - 6u * p;           // 16B group 0..5
      const unsigned iz = p / 12u;
      const unsigned iy = p - 12u * iz;
      const int zz = (z0 + (int)iz - 2) & (HZ - 1);
      const int yy = (y0 + (int)iy - 2) & (NN - 1);
      const int xb = (x0 - 4 + 4 * (int)t) & (NN - 1);
      g2l16(&anat[(zz << 14) | (yy << 7) | xb], &in_t[q * 4]);
    }
  }
  __syncthreads();

  // ---- Sort phase: 2 own core rows (straight-line) + 776 halo rows ----
  unsigned lo0, hi0, lo1, hi1;
  {
    unsigned od[4], h8;
    const int rz = 2 * zl + 1, ry = yl + 1, rx = xl + 1;
    const int ru = (rz * RY + ry) * RX + rx;
    sort_row<true>(in_t, rz, ry, rx, od, h8, lo0, hi0);
    *(uint4*)&tA[(unsigned)ru * 4] = make_uint4(od[0], od[1], od[2], od[3]);
    tB0h[ru] = (unsigned short)h8;
  }
  {
    unsigned od[4], h8;
    const int rz = 2 * zl + 2, ry = yl + 1, rx = xl + 1;
    const int ru = (rz * RY + ry) * RX + rx;
    sort_row<true>(in_t, rz, ry, rx, od, h8, lo1, hi1);
    *(uint4*)&tA[(unsigned)ru * 4] = make_uint4(od[0], od[1], od[2], od[3]);
    tB0h[ru] = (unsigned short)h8;
  }
  #pragma unroll 1
  for (int s = 0; s < 2; ++s) {
    const int idx = s * 512 + tid;
    if (idx < NHALO) {
      const int ru = (int)HALO[idx];
      const int rz = ru / (RY * RX);
      const int rem = ru - (RY * RX) * rz;
      const int ry = rem / RX, rx = rem - RX * ry;
      unsigned od[4], h8, lo, hi;
      sort_row<false>(in_t, rz, ry, rx, od, h8, lo, hi);
      *(uint4*)&tA[(unsigned)ru * 4] = make_uint4(od[0], od[1], od[2], od[3]);
      tB0h[ru] = (unsigned short)h8;
    }
  }
  __syncthreads();

  // ---- Weights phase: 2 core voxels per thread; direct stores ----
  const float ks = ksig[0];
  const _Float16 epsh = (_Float16)1e-6f;
  const f16x2 eps2 = {epsh, epsh};

  #pragma unroll
  for (int vz = 0; vz < 2; ++vz) {
    const int zv = 2 * zl + vz;               // core z offset 0..7
    const unsigned lo = (vz == 0) ? lo0 : lo1;
    const unsigned hi = (vz == 0) ? hi0 : hi1;

    const int rho_own = ((zv + 1) * RY + (yl + 1)) * RX + (xl + 1);
    const uint4 a = *(const uint4*)&tA[rho_own * 4];
    const unsigned b0 = (unsigned)tB0h[rho_own];
    f16x2 wh[5];
    wh[0] = __builtin_bit_cast(f16x2, a.x);
    wh[1] = __builtin_bit_cast(f16x2, a.y);
    wh[2] = __builtin_bit_cast(f16x2, a.z);
    wh[3] = __builtin_bit_cast(f16x2, a.w);
    wh[4] = __builtin_bit_cast(f16x2, b0);    // hi half = 0 pad

    // Decode all 9 neighbor row addresses, then batch-issue all 18 reads.
    int rho[KSEL];
    #pragma unroll
    for (int j = 0; j < KSEL; ++j) {
      const unsigned c = (j < 6) ? ((lo >> (5 * j)) & 31u)
                                 : ((hi >> (5 * (j - 6))) & 31u);
      const unsigned czi = (c * 57u) >> 9;
      const unsigned rem = c - 9u * czi;
      const unsigned cyi = (rem * 11u) >> 5;
      const unsigned cxi = rem - 3u * cyi;
      rho[j] = ((zv + (int)czi) * RY + (yl + (int)cyi)) * RX + (xl + (int)cxi);
    }
    uint4 na[KSEL];
    unsigned nb[KSEL];
    #pragma unroll
    for (int j = 0; j < KSEL; ++j) {
      na[j] = *(const uint4*)&tA[rho[j] * 4];
      nb[j] = (unsigned)tB0h[rho[j]];
    }

    // sigma with ddof=1 (two-pass, matches jnp.std).
    float ws[KSEL];
    #pragma unroll
    for (int l = 0; l < KSEL; ++l) ws[l] = (float)wh[l >> 1][l & 1];
    float mean = 0.f;
    #pragma unroll
    for (int l = 0; l < KSEL; ++l) mean += ws[l];
    mean *= (1.0f / 9.0f);
    float var = 0.f;
    #pragma unroll
    for (int l = 0; l < KSEL; ++l) { const float t = ws[l] - mean; var += t * t; }
    var *= (1.0f / 8.0f);
    const float sigma = sqrtf(var);

    // log2(e) folded in: e[j] = exp2(logit[j] - mx)
    const float inv2 = (sigma == 0.f)
        ? 0.f
        : 1.4426950408889634f / (2.0f * ks * ks * sigma * sigma);

    float logit[KSEL];
    #pragma unroll
    for (int j = 0; j < KSEL; ++j) {
      const f16x2 nh0 = __builtin_bit_cast(f16x2, na[j].x);
      const f16x2 nh1 = __builtin_bit_cast(f16x2, na[j].y);
      const f16x2 nh2 = __builtin_bit_cast(f16x2, na[j].z);
      const f16x2 nh3 = __builtin_bit_cast(f16x2, na[j].w);
      const f16x2 nh4 = __builtin_bit_cast(f16x2, nb[j]);
      float s = 0.f;
      f16x2 dd;
      dd = (wh[0] - nh0) + eps2; s = __builtin_amdgcn_fdot2(dd, dd, s, false);
      dd = (wh[1] - nh1) + eps2; s = __builtin_amdgcn_fdot2(dd, dd, s, false);
      dd = (wh[2] - nh2) + eps2; s = __builtin_amdgcn_fdot2(dd, dd, s, false);
      dd = (wh[3] - nh3) + eps2; s = __builtin_amdgcn_fdot2(dd, dd, s, false);
      dd = (wh[4] - nh4) + eps2; s = __builtin_amdgcn_fdot2(dd, dd, s, false);
      logit[j] = -s * inv2;
    }

    // softmax (exp2 domain) over the 9 logits
    float mx = logit[0];
    #pragma unroll
    for (int j = 1; j < KSEL; ++j) mx = fmaxf(mx, logit[j]);
    float sum = 0.f;
    float e[KSEL];
    #pragma unroll
    for (int j = 0; j < KSEL; ++j) { e[j] = exp2f(logit[j] - mx); sum += e[j]; }
    const float rs = 1.0f / sum;

    // Direct stores: lane xl-consecutive voxels -> dense 576 B runs per
    // 16-lane group; every output cache line fully covered block-wide.
    const unsigned vb = (unsigned)(((z0 + zv) << 14) | ((y0 + yl) << 7) |
                                   (x0 + xl));
    float* op = out + (size_t)vb * 9;
    #pragma unroll
    for (int j = 0; j < KSEL; ++j) op[j] = e[j] * rs;
  }
}

// ---------------------------------------------------------------------------
// d_in: [0] input (P floats), [1] ksigma (1 float), [2] k (int), [3] w (int)
// d_ws: unused (fully fused).
// ---------------------------------------------------------------------------
extern "C" void kernel_launch(void* const* d_in, const int* in_sizes, int n_in,
                              void* d_out, int out_size, void* d_ws, size_t ws_size,
                              hipStream_t stream) {
  const float* anat = (const float*)d_in[0];
  const float* ksig = (const float*)d_in[1];
  buildk_fused7<<<P / NCORE, 512, 0, stream>>>(anat, ksig, (float*)d_out);
}